// Round 1
// baseline (1518.528 us; speedup 1.0000x reference)
//
#include <hip/hip_runtime.h>

// Problem constants (match reference setup_inputs)
#define NN 100000     // nodes
#define NE 1600000    // edges
#define NG 512        // graphs
#define C_IN 3
#define C_H1 64
#define C_H2 128
#define C_OUT 2

// ---------------- degree / norm ----------------
__global__ void k_deg(const int* __restrict__ ei, float* __restrict__ deg) {
    int e = blockIdx.x * blockDim.x + threadIdx.x;
    if (e < NE) atomicAdd(&deg[ei[NE + e]], 1.0f);   // count at edge targets
}

__global__ void k_dinv(float* __restrict__ d) {
    int i = blockIdx.x * blockDim.x + threadIdx.x;
    if (i < NN) d[i] = rsqrtf(d[i] + 1.0f);          // deg + self-loop
}

// ---------------- layer 1: xw1 = x @ W1 ; agg1 init = dinv^2 * xw1 ----------------
__global__ void k_mm1(const float* __restrict__ x, const float* __restrict__ W1,
                      const float* __restrict__ dinv,
                      float* __restrict__ xw1, float* __restrict__ agg1) {
    int t = blockIdx.x * blockDim.x + threadIdx.x;
    if (t >= NN * C_H1) return;
    int n = t >> 6, c = t & 63;
    float v = x[n * 3] * W1[c] + x[n * 3 + 1] * W1[64 + c] + x[n * 3 + 2] * W1[128 + c];
    xw1[t] = v;
    float di = dinv[n];
    agg1[t] = di * di * v;   // self-loop contribution (bias applied by consumer)
}

// ---------------- layer 1 edge scatter: agg1[dst] += dinv[s]*dinv[d] * xw1[src] ----
__global__ void k_agg1(const int* __restrict__ ei, const float* __restrict__ dinv,
                       const float* __restrict__ xw1, float* __restrict__ agg1) {
    int t = blockIdx.x * blockDim.x + threadIdx.x;   // one thread per (edge, channel)
    if (t >= NE * 64) return;
    int e = t >> 6, c = t & 63;
    int s = ei[e], d = ei[NE + e];
    float nrm = dinv[s] * dinv[d];
    atomicAdd(&agg1[(d << 6) + c], nrm * xw1[(s << 6) + c]);
}

// ---------------- layer 2: h1 = relu(agg1+b1); xw2 = h1 @ W2 ; agg2 init ----------
__global__ void k_mm2(const float* __restrict__ agg1, const float* __restrict__ b1,
                      const float* __restrict__ W2, const float* __restrict__ dinv,
                      float* __restrict__ xw2, float* __restrict__ agg2) {
    int t = blockIdx.x * blockDim.x + threadIdx.x;
    if (t >= NN * C_H2) return;
    int n = t >> 7, c = t & 127;
    const float* a = agg1 + (n << 6);
    float acc = 0.f;
#pragma unroll 8
    for (int k = 0; k < C_H1; ++k) {
        float h = fmaxf(a[k] + b1[k], 0.f);          // relu fused on read
        acc = fmaf(h, W2[(k << 7) + c], acc);
    }
    xw2[t] = acc;
    float di = dinv[n];
    agg2[t] = di * di * acc;
}

// ---------------- layer 2 edge scatter ----------------
__global__ void k_agg2(const int* __restrict__ ei, const float* __restrict__ dinv,
                       const float* __restrict__ xw2, float* __restrict__ agg2) {
    int t = blockIdx.x * blockDim.x + threadIdx.x;   // one thread per (edge, channel)
    if (t >= 0x7FFFFFFF) return;                     // grid sized exactly: NE*128 threads
    int e = t >> 7, c = t & 127;
    int s = ei[e], d = ei[NE + e];
    float nrm = dinv[s] * dinv[d];
    atomicAdd(&agg2[(d << 7) + c], nrm * xw2[(s << 7) + c]);
}

// ---------------- pooling (batch sorted -> contiguous ranges) + FC ----------------
__device__ __forceinline__ int lower_bound(const int* __restrict__ a, int n, int key) {
    int lo = 0, hi = n;
    while (lo < hi) { int mid = (lo + hi) >> 1; if (a[mid] < key) lo = mid + 1; else hi = mid; }
    return lo;
}

__global__ void k_pool(const float* __restrict__ agg2, const float* __restrict__ b2,
                       const int* __restrict__ batch, const float* __restrict__ Wfc,
                       const float* __restrict__ bfc, float* __restrict__ out) {
    int g = blockIdx.x;
    int start = lower_bound(batch, NN, g);
    int end   = lower_bound(batch, NN, g + 1);
    int tid = threadIdx.x;
    int c = tid & 127, half = tid >> 7;
    float bias = b2[c];
    float acc = 0.f;
    for (int i = start + half; i < end; i += 2)
        acc += fmaxf(agg2[i * C_H2 + c] + bias, 0.f); // relu fused on read
    __shared__ float sh[256];
    __shared__ float pool[C_H2];
    sh[tid] = acc;
    __syncthreads();
    if (tid < C_H2) {
        float cnt = (float)(end - start);
        pool[tid] = (sh[tid] + sh[tid + 128]) / fmaxf(cnt, 1.0f);
    }
    __syncthreads();
    if (tid < C_OUT) {
        float s = bfc[tid];
        for (int cc = 0; cc < C_H2; ++cc)
            s = fmaf(pool[cc], Wfc[cc * C_OUT + tid], s);
        out[g * C_OUT + tid] = s;
    }
}

extern "C" void kernel_launch(void* const* d_in, const int* in_sizes, int n_in,
                              void* d_out, int out_size, void* d_ws, size_t ws_size,
                              hipStream_t stream) {
    const float* x     = (const float*)d_in[0];
    const int*   ei    = (const int*)d_in[1];   // [2, E]: row0 = src, row1 = dst
    const int*   batch = (const int*)d_in[2];   // [N], sorted
    const float* W1    = (const float*)d_in[3];
    const float* b1    = (const float*)d_in[4];
    const float* W2    = (const float*)d_in[5];
    const float* b2    = (const float*)d_in[6];
    const float* Wfc   = (const float*)d_in[7];
    const float* bfc   = (const float*)d_in[8];
    float* out = (float*)d_out;

    // workspace carve-out (~154 MB)
    char* p = (char*)d_ws;
    auto alloc = [&](size_t bytes) { char* r = p; p += (bytes + 255) & ~size_t(255); return r; };
    float* dinv = (float*)alloc((size_t)NN * 4);
    float* xw1  = (float*)alloc((size_t)NN * C_H1 * 4);
    float* agg1 = (float*)alloc((size_t)NN * C_H1 * 4);
    float* xw2  = (float*)alloc((size_t)NN * C_H2 * 4);
    float* agg2 = (float*)alloc((size_t)NN * C_H2 * 4);

    hipMemsetAsync(dinv, 0, (size_t)NN * 4, stream);
    k_deg <<<(NE + 255) / 256, 256, 0, stream>>>(ei, dinv);
    k_dinv<<<(NN + 255) / 256, 256, 0, stream>>>(dinv);
    k_mm1 <<<(NN * C_H1 + 255) / 256, 256, 0, stream>>>(x, W1, dinv, xw1, agg1);
    k_agg1<<<(NE * 64) / 256, 256, 0, stream>>>(ei, dinv, xw1, agg1);      // 400000 blocks, exact
    k_mm2 <<<(NN * C_H2 + 255) / 256, 256, 0, stream>>>(agg1, b1, W2, dinv, xw2, agg2);
    k_agg2<<<(NE * 128) / 256, 256, 0, stream>>>(ei, dinv, xw2, agg2);     // 800000 blocks, exact
    k_pool<<<NG, 256, 0, stream>>>(agg2, b2, batch, Wfc, bfc, out);
}

// Round 2
// 1133.280 us; speedup vs baseline: 1.3399x; 1.3399x over previous
//
#include <hip/hip_runtime.h>

#define NN 100000     // nodes
#define NE 1600000    // edges
#define NG 512        // graphs
#define C_H1 64
#define C_H2 128
#define C_OUT 2

// ---------------- degree histogram (at dst) ----------------
__global__ void k_deg(const int* __restrict__ ei, int* __restrict__ deg) {
    int e = blockIdx.x * blockDim.x + threadIdx.x;
    if (e < NE) atomicAdd(&deg[ei[NE + e]], 1);
}

__global__ void k_dinv(const int* __restrict__ deg, float* __restrict__ dinv) {
    int i = blockIdx.x * blockDim.x + threadIdx.x;
    if (i < NN) dinv[i] = rsqrtf((float)deg[i] + 1.0f);
}

// ---------------- single-block exclusive scan over deg -> row_ptr, cursor ----------
__global__ void k_scan(const int* __restrict__ deg, int* __restrict__ row_ptr,
                       int* __restrict__ cursor) {
    __shared__ int sh[1024];
    const int T = 1024;
    const int CH = (NN + T - 1) / T;           // 98
    int tid = threadIdx.x;
    int base = tid * CH;
    int sum = 0;
    for (int i = 0; i < CH; ++i) {
        int idx = base + i;
        if (idx < NN) sum += deg[idx];
    }
    sh[tid] = sum;
    __syncthreads();
    for (int off = 1; off < T; off <<= 1) {    // Hillis-Steele inclusive scan
        int v = (tid >= off) ? sh[tid - off] : 0;
        __syncthreads();
        sh[tid] += v;
        __syncthreads();
    }
    int run = (tid == 0) ? 0 : sh[tid - 1];    // exclusive offset of this chunk
    for (int i = 0; i < CH; ++i) {
        int idx = base + i;
        if (idx < NN) {
            row_ptr[idx] = run;
            cursor[idx]  = run;
            run += deg[idx];
        }
    }
    if (tid == T - 1) row_ptr[NN] = run;       // == NE
}

// ---------------- scatter edges into dst-CSR: packed (src, norm) ----------------
__global__ void k_scatter(const int* __restrict__ ei, const float* __restrict__ dinv,
                          int* __restrict__ cursor, int2* __restrict__ ed) {
    int e = blockIdx.x * blockDim.x + threadIdx.x;
    if (e >= NE) return;
    int s = ei[e], d = ei[NE + e];
    int pos = atomicAdd(&cursor[d], 1);
    int2 v; v.x = s; v.y = __float_as_int(dinv[s] * dinv[d]);
    ed[pos] = v;
}

// ---------------- layer 1 dense: xw1 = x @ W1 ----------------
__global__ void k_mm1(const float* __restrict__ x, const float* __restrict__ W1,
                      float* __restrict__ xw1) {
    int t = blockIdx.x * blockDim.x + threadIdx.x;
    if (t >= NN * C_H1) return;
    int n = t >> 6, c = t & 63;
    xw1[t] = x[n * 3] * W1[c] + x[n * 3 + 1] * W1[64 + c] + x[n * 3 + 2] * W1[128 + c];
}

// ---------------- layer 1 gather: h1 = relu(sum + self + b1) ----------------
__global__ void k_gather1(const int* __restrict__ row_ptr, const int2* __restrict__ ed,
                          const float* __restrict__ dinv, const float* __restrict__ xw1,
                          const float* __restrict__ b1, float* __restrict__ h1) {
    int t = blockIdx.x * blockDim.x + threadIdx.x;   // (node, channel); wave = 1 node
    if (t >= NN * C_H1) return;
    int n = t >> 6, c = t & 63;
    float di = dinv[n];
    float acc = di * di * xw1[t];                    // self-loop
    int beg = row_ptr[n], end = row_ptr[n + 1];
    for (int j = beg; j < end; ++j) {
        int2 v = ed[j];                              // wave-uniform 8B load
        acc = fmaf(__int_as_float(v.y), xw1[(v.x << 6) + c], acc);
    }
    h1[t] = fmaxf(acc + b1[c], 0.f);
}

// ---------------- layer 2 dense: xw2 = h1 @ W2 (W2 staged in LDS) ----------------
__global__ void k_mm2(const float* __restrict__ h1, const float* __restrict__ W2,
                      float* __restrict__ xw2) {
    __shared__ float w[C_H1 * C_H2];                 // 32 KiB
    int tid = threadIdx.x;
    for (int i = tid; i < C_H1 * C_H2; i += 256) w[i] = W2[i];
    __syncthreads();
    int t = blockIdx.x * 256 + tid;
    int n = t >> 7, c = t & 127;
    const float* a = h1 + (n << 6);
    float acc = 0.f;
#pragma unroll
    for (int k = 0; k < C_H1; ++k)
        acc = fmaf(a[k], w[(k << 7) + c], acc);
    xw2[t] = acc;
}

// ---------------- layer 2 gather: h2 = relu(sum + self + b2) ----------------
__global__ void k_gather2(const int* __restrict__ row_ptr, const int2* __restrict__ ed,
                          const float* __restrict__ dinv, const float* __restrict__ xw2,
                          const float* __restrict__ b2, float* __restrict__ h2) {
    int t = blockIdx.x * blockDim.x + threadIdx.x;   // (node, channel); 2 waves/node
    if (t >= NN * C_H2) return;
    int n = t >> 7, c = t & 127;
    float di = dinv[n];
    float acc = di * di * xw2[t];
    int beg = row_ptr[n], end = row_ptr[n + 1];
    for (int j = beg; j < end; ++j) {
        int2 v = ed[j];
        acc = fmaf(__int_as_float(v.y), xw2[(v.x << 7) + c], acc);
    }
    h2[t] = fmaxf(acc + b2[c], 0.f);
}

// ---------------- pooling (batch sorted -> contiguous ranges) + FC ----------------
__device__ __forceinline__ int lower_bound(const int* __restrict__ a, int n, int key) {
    int lo = 0, hi = n;
    while (lo < hi) { int mid = (lo + hi) >> 1; if (a[mid] < key) lo = mid + 1; else hi = mid; }
    return lo;
}

__global__ void k_pool(const float* __restrict__ h2, const int* __restrict__ batch,
                       const float* __restrict__ Wfc, const float* __restrict__ bfc,
                       float* __restrict__ out) {
    int g = blockIdx.x;
    int start = lower_bound(batch, NN, g);
    int end   = lower_bound(batch, NN, g + 1);
    int tid = threadIdx.x;
    int c = tid & 127, half = tid >> 7;
    float acc = 0.f;
    for (int i = start + half; i < end; i += 2)
        acc += h2[i * C_H2 + c];
    __shared__ float sh[256];
    __shared__ float pool[C_H2];
    sh[tid] = acc;
    __syncthreads();
    if (tid < C_H2) {
        float cnt = (float)(end - start);
        pool[tid] = (sh[tid] + sh[tid + 128]) / fmaxf(cnt, 1.0f);
    }
    __syncthreads();
    if (tid < C_OUT) {
        float s = bfc[tid];
        for (int cc = 0; cc < C_H2; ++cc)
            s = fmaf(pool[cc], Wfc[cc * C_OUT + tid], s);
        out[g * C_OUT + tid] = s;
    }
}

extern "C" void kernel_launch(void* const* d_in, const int* in_sizes, int n_in,
                              void* d_out, int out_size, void* d_ws, size_t ws_size,
                              hipStream_t stream) {
    const float* x     = (const float*)d_in[0];
    const int*   ei    = (const int*)d_in[1];   // [2, E]: row0 = src, row1 = dst
    const int*   batch = (const int*)d_in[2];
    const float* W1    = (const float*)d_in[3];
    const float* b1    = (const float*)d_in[4];
    const float* W2    = (const float*)d_in[5];
    const float* b2    = (const float*)d_in[6];
    const float* Wfc   = (const float*)d_in[7];
    const float* bfc   = (const float*)d_in[8];
    float* out = (float*)d_out;

    // workspace carve-out (~117 MB): h2 aliases the dead xw1+h1 region
    char* p = (char*)d_ws;
    auto alloc = [&](size_t bytes) { char* r = p; p += (bytes + 255) & ~size_t(255); return r; };
    int*   deg     = (int*)  alloc((size_t)NN * 4);
    float* dinv    = (float*)alloc((size_t)NN * 4);
    int*   row_ptr = (int*)  alloc((size_t)(NN + 1) * 4);
    int*   cursor  = (int*)  alloc((size_t)NN * 4);
    int2*  ed      = (int2*) alloc((size_t)NE * 8);
    char*  regionA = (char*) alloc((size_t)NN * C_H2 * 4);   // xw1 | h1  (later h2)
    float* xw2     = (float*)alloc((size_t)NN * C_H2 * 4);
    float* xw1 = (float*)regionA;
    float* h1  = (float*)(regionA + (size_t)NN * C_H1 * 4);
    float* h2  = (float*)regionA;                            // alias: xw1/h1 dead by then

    hipMemsetAsync(deg, 0, (size_t)NN * 4, stream);
    k_deg    <<<NE / 256, 256, 0, stream>>>(ei, deg);
    k_dinv   <<<(NN + 255) / 256, 256, 0, stream>>>(deg, dinv);
    k_scan   <<<1, 1024, 0, stream>>>(deg, row_ptr, cursor);
    k_scatter<<<NE / 256, 256, 0, stream>>>(ei, dinv, cursor, ed);
    k_mm1    <<<(NN * C_H1) / 256, 256, 0, stream>>>(x, W1, xw1);
    k_gather1<<<(NN * C_H1) / 256, 256, 0, stream>>>(row_ptr, ed, dinv, xw1, b1, h1);
    k_mm2    <<<(NN * C_H2) / 256, 256, 0, stream>>>(h1, W2, xw2);
    k_gather2<<<(NN * C_H2) / 256, 256, 0, stream>>>(row_ptr, ed, dinv, xw2, b2, h2);
    k_pool   <<<NG, 256, 0, stream>>>(h2, batch, Wfc, bfc, out);
}

// Round 3
// 765.844 us; speedup vs baseline: 1.9828x; 1.4798x over previous
//
#include <hip/hip_runtime.h>

#define NN 100000     // nodes
#define NE 1600000    // edges
#define NG 512        // graphs
#define C_H1 64
#define C_H2 128
#define C_OUT 2

// ---------------- degree histogram (at dst) ----------------
__global__ void k_deg(const int* __restrict__ ei, int* __restrict__ deg) {
    int e = blockIdx.x * blockDim.x + threadIdx.x;
    if (e < NE) atomicAdd(&deg[ei[NE + e]], 1);
}

__global__ void k_dinv(const int* __restrict__ deg, float* __restrict__ dinv) {
    int i = blockIdx.x * blockDim.x + threadIdx.x;
    if (i < NN) dinv[i] = rsqrtf((float)deg[i] + 1.0f);
}

// ---------------- single-block exclusive scan over deg -> row_ptr, cursor ----------
__global__ void k_scan(const int* __restrict__ deg, int* __restrict__ row_ptr,
                       int* __restrict__ cursor) {
    __shared__ int sh[1024];
    const int T = 1024;
    const int CH = (NN + T - 1) / T;           // 98
    int tid = threadIdx.x;
    int base = tid * CH;
    int sum = 0;
    for (int i = 0; i < CH; ++i) {
        int idx = base + i;
        if (idx < NN) sum += deg[idx];
    }
    sh[tid] = sum;
    __syncthreads();
    for (int off = 1; off < T; off <<= 1) {    // Hillis-Steele inclusive scan
        int v = (tid >= off) ? sh[tid - off] : 0;
        __syncthreads();
        sh[tid] += v;
        __syncthreads();
    }
    int run = (tid == 0) ? 0 : sh[tid - 1];
    for (int i = 0; i < CH; ++i) {
        int idx = base + i;
        if (idx < NN) {
            row_ptr[idx] = run;
            cursor[idx]  = run;
            run += deg[idx];
        }
    }
    if (tid == T - 1) row_ptr[NN] = run;
}

// ---------------- scatter edges into dst-CSR: packed (src, norm) ----------------
__global__ void k_scatter(const int* __restrict__ ei, const float* __restrict__ dinv,
                          int* __restrict__ cursor, int2* __restrict__ ed) {
    int e = blockIdx.x * blockDim.x + threadIdx.x;
    if (e >= NE) return;
    int s = ei[e], d = ei[NE + e];
    int pos = atomicAdd(&cursor[d], 1);
    int2 v; v.x = s; v.y = __float_as_int(dinv[s] * dinv[d]);
    ed[pos] = v;
}

// ---------------- layer 1 aggregate FIRST (3 channels, x is L2-resident) ----------
// aggx = Ahat @ x   (one thread per node, 3 accumulators)
__global__ void k_aggx(const int* __restrict__ row_ptr, const int2* __restrict__ ed,
                       const float* __restrict__ dinv, const float* __restrict__ x,
                       float* __restrict__ aggx) {
    int n = blockIdx.x * blockDim.x + threadIdx.x;
    if (n >= NN) return;
    float di = dinv[n];
    float s2 = di * di;
    float a0 = s2 * x[n * 3], a1 = s2 * x[n * 3 + 1], a2 = s2 * x[n * 3 + 2];
    int beg = row_ptr[n], end = row_ptr[n + 1];
    for (int j = beg; j < end; ++j) {
        int2 v = ed[j];
        float w = __int_as_float(v.y);
        const float* xs = x + v.x * 3;
        a0 = fmaf(w, xs[0], a0);
        a1 = fmaf(w, xs[1], a1);
        a2 = fmaf(w, xs[2], a2);
    }
    aggx[n * 3]     = a0;
    aggx[n * 3 + 1] = a1;
    aggx[n * 3 + 2] = a2;
}

// ---------------- h1 = relu(aggx @ W1 + b1) ----------------
__global__ void k_h1(const float* __restrict__ aggx, const float* __restrict__ W1,
                     const float* __restrict__ b1, float* __restrict__ h1) {
    int t = blockIdx.x * blockDim.x + threadIdx.x;
    if (t >= NN * C_H1) return;
    int n = t >> 6, c = t & 63;
    float v = aggx[n * 3] * W1[c] + aggx[n * 3 + 1] * W1[64 + c]
            + aggx[n * 3 + 2] * W1[128 + c] + b1[c];
    h1[t] = fmaxf(v, 0.f);
}

// ---------------- layer 2 aggregate (64 channels): agg1 = Ahat @ h1 --------------
__global__ void k_gather2(const int* __restrict__ row_ptr, const int2* __restrict__ ed,
                          const float* __restrict__ dinv, const float* __restrict__ h1,
                          float* __restrict__ agg1) {
    int t = blockIdx.x * blockDim.x + threadIdx.x;   // wave = one node (64 ch)
    if (t >= NN * C_H1) return;
    int n = t >> 6, c = t & 63;
    float di = dinv[n];
    float acc = di * di * h1[t];                     // self-loop
    int beg = row_ptr[n], end = row_ptr[n + 1];
    int j = beg;
    // unroll x4 for memory-level parallelism (latency-bound loop)
    for (; j + 3 < end; j += 4) {
        int2 v0 = ed[j], v1 = ed[j + 1], v2 = ed[j + 2], v3 = ed[j + 3];
        float f0 = h1[(v0.x << 6) + c];
        float f1 = h1[(v1.x << 6) + c];
        float f2 = h1[(v2.x << 6) + c];
        float f3 = h1[(v3.x << 6) + c];
        acc = fmaf(__int_as_float(v0.y), f0, acc);
        acc = fmaf(__int_as_float(v1.y), f1, acc);
        acc = fmaf(__int_as_float(v2.y), f2, acc);
        acc = fmaf(__int_as_float(v3.y), f3, acc);
    }
    for (; j < end; ++j) {
        int2 v = ed[j];
        acc = fmaf(__int_as_float(v.y), h1[(v.x << 6) + c], acc);
    }
    agg1[t] = acc;   // NO bias/relu here: h2 = relu(agg1 @ W2 + b2)
}

// ---------------- fused: h2 = relu(agg1 @ W2 + b2), pooled += h2 -----------------
// 16 nodes per block; 256 threads = 2 rows x 128 ch; run-length flush atomics.
__global__ void k_mm2pool(const float* __restrict__ agg1, const float* __restrict__ W2,
                          const float* __restrict__ b2, const int* __restrict__ batch,
                          float* __restrict__ pooled) {
    __shared__ float w[C_H1 * C_H2];                 // 32 KiB
    int tid = threadIdx.x;
    for (int i = tid; i < C_H1 * C_H2; i += 256) w[i] = W2[i];
    __syncthreads();
    int c = tid & 127, half = tid >> 7;
    int base = blockIdx.x * 16;                      // NN % 16 == 0
    float bias = b2[c];
    int run_g = -1;
    float run_sum = 0.f;
    for (int i = half; i < 16; i += 2) {
        int n = base + i;
        const float* a = agg1 + (n << 6);
        float acc = bias;
#pragma unroll
        for (int k = 0; k < C_H1; ++k)
            acc = fmaf(a[k], w[(k << 7) + c], acc);
        float h2 = fmaxf(acc, 0.f);
        int g = batch[n];
        if (g != run_g) {
            if (run_g >= 0) atomicAdd(&pooled[(run_g << 7) + c], run_sum);
            run_g = g; run_sum = h2;
        } else {
            run_sum += h2;
        }
    }
    if (run_g >= 0) atomicAdd(&pooled[(run_g << 7) + c], run_sum);
}

// ---------------- FC: out = (pooled/cnt) @ Wfc + bfc ----------------
__device__ __forceinline__ int lower_bound(const int* __restrict__ a, int n, int key) {
    int lo = 0, hi = n;
    while (lo < hi) { int mid = (lo + hi) >> 1; if (a[mid] < key) lo = mid + 1; else hi = mid; }
    return lo;
}

__global__ void k_fc(const float* __restrict__ pooled, const int* __restrict__ batch,
                     const float* __restrict__ Wfc, const float* __restrict__ bfc,
                     float* __restrict__ out) {
    int t = blockIdx.x * blockDim.x + threadIdx.x;
    if (t >= NG * C_OUT) return;
    int g = t >> 1, o = t & 1;
    int start = lower_bound(batch, NN, g);
    int end   = lower_bound(batch, NN, g + 1);
    float inv = 1.f / fmaxf((float)(end - start), 1.f);
    float s = bfc[o];
    for (int cc = 0; cc < C_H2; ++cc)
        s = fmaf(pooled[(g << 7) + cc] * inv, Wfc[cc * C_OUT + o], s);
    out[t] = s;
}

extern "C" void kernel_launch(void* const* d_in, const int* in_sizes, int n_in,
                              void* d_out, int out_size, void* d_ws, size_t ws_size,
                              hipStream_t stream) {
    const float* x     = (const float*)d_in[0];
    const int*   ei    = (const int*)d_in[1];   // [2, E]: row0 = src, row1 = dst
    const int*   batch = (const int*)d_in[2];
    const float* W1    = (const float*)d_in[3];
    const float* b1    = (const float*)d_in[4];
    const float* W2    = (const float*)d_in[5];
    const float* b2    = (const float*)d_in[6];
    const float* Wfc   = (const float*)d_in[7];
    const float* bfc   = (const float*)d_in[8];
    float* out = (float*)d_out;

    // workspace carve-out (~66 MB)
    char* p = (char*)d_ws;
    auto alloc = [&](size_t bytes) { char* r = p; p += (bytes + 255) & ~size_t(255); return r; };
    int*   deg     = (int*)  alloc((size_t)NN * 4);
    float* dinv    = (float*)alloc((size_t)NN * 4);
    int*   row_ptr = (int*)  alloc((size_t)(NN + 1) * 4);
    int*   cursor  = (int*)  alloc((size_t)NN * 4);
    int2*  ed      = (int2*) alloc((size_t)NE * 8);
    float* aggx    = (float*)alloc((size_t)NN * 3 * 4);
    float* h1      = (float*)alloc((size_t)NN * C_H1 * 4);
    float* agg1    = (float*)alloc((size_t)NN * C_H1 * 4);
    float* pooled  = (float*)alloc((size_t)NG * C_H2 * 4);

    hipMemsetAsync(deg, 0, (size_t)NN * 4, stream);
    hipMemsetAsync(pooled, 0, (size_t)NG * C_H2 * 4, stream);
    k_deg    <<<NE / 256, 256, 0, stream>>>(ei, deg);
    k_dinv   <<<(NN + 255) / 256, 256, 0, stream>>>(deg, dinv);
    k_scan   <<<1, 1024, 0, stream>>>(deg, row_ptr, cursor);
    k_scatter<<<NE / 256, 256, 0, stream>>>(ei, dinv, cursor, ed);
    k_aggx   <<<(NN + 255) / 256, 256, 0, stream>>>(row_ptr, ed, dinv, x, aggx);
    k_h1     <<<(NN * C_H1) / 256, 256, 0, stream>>>(aggx, W1, b1, h1);
    k_gather2<<<(NN * C_H1) / 256, 256, 0, stream>>>(row_ptr, ed, dinv, h1, agg1);
    k_mm2pool<<<NN / 16, 256, 0, stream>>>(agg1, W2, b2, batch, pooled);
    k_fc     <<<(NG * C_OUT + 255) / 256, 256, 0, stream>>>(pooled, batch, Wfc, bfc, out);
}

// Round 4
// 505.502 us; speedup vs baseline: 3.0040x; 1.5150x over previous
//
#include <hip/hip_runtime.h>

#define NN 100000     // nodes
#define NE 1600000    // edges
#define NG 512        // graphs
#define C_H1 64
#define C_H2 128
#define C_OUT 2

#define SCAN_CHUNK 512
#define SCAN_B ((NN + SCAN_CHUNK - 1) / SCAN_CHUNK)   // 196

// ---------------- degree histogram (at dst) ----------------
__global__ void k_deg(const int* __restrict__ ei, int* __restrict__ deg) {
    int e = blockIdx.x * blockDim.x + threadIdx.x;
    if (e < NE) atomicAdd(&deg[ei[NE + e]], 1);
}

__global__ void k_dinv(const int* __restrict__ deg, float* __restrict__ dinv) {
    int i = blockIdx.x * blockDim.x + threadIdx.x;
    if (i < NN) dinv[i] = rsqrtf((float)deg[i] + 1.0f);
}

// ---------------- hierarchical scan phase 1: per-block sums ----------------
__global__ void k_bsum(const int* __restrict__ deg, int* __restrict__ bsum) {
    __shared__ int sh[256];
    int tid = threadIdx.x;
    int base = blockIdx.x * SCAN_CHUNK + tid * 2;
    int s = 0;
    if (base < NN)     s += deg[base];
    if (base + 1 < NN) s += deg[base + 1];
    sh[tid] = s;
    __syncthreads();
    for (int off = 128; off > 0; off >>= 1) {
        if (tid < off) sh[tid] += sh[tid + off];
        __syncthreads();
    }
    if (tid == 0) bsum[blockIdx.x] = sh[0];
}

// ---------------- phase 2: single small block scans the 196 block sums -----------
__global__ void k_bscan(const int* __restrict__ bsum, int* __restrict__ boff,
                        int* __restrict__ row_ptr) {
    __shared__ int sh[256];
    int tid = threadIdx.x;
    sh[tid] = (tid < SCAN_B) ? bsum[tid] : 0;
    __syncthreads();
    for (int off = 1; off < 256; off <<= 1) {
        int v = (tid >= off) ? sh[tid - off] : 0;
        __syncthreads();
        sh[tid] += v;
        __syncthreads();
    }
    if (tid < SCAN_B) boff[tid] = (tid == 0) ? 0 : sh[tid - 1];
    if (tid == 255) row_ptr[NN] = sh[SCAN_B - 1];   // total == NE
}

// ---------------- phase 3: in-block exclusive scan + write row_ptr/cursor --------
__global__ void k_bwrite(const int* __restrict__ deg, const int* __restrict__ boff,
                         int* __restrict__ row_ptr, int* __restrict__ cursor) {
    __shared__ int sh[256];
    int tid = threadIdx.x;
    int base = blockIdx.x * SCAN_CHUNK + tid * 2;
    int d0 = (base < NN)     ? deg[base]     : 0;
    int d1 = (base + 1 < NN) ? deg[base + 1] : 0;
    sh[tid] = d0 + d1;
    __syncthreads();
    for (int off = 1; off < 256; off <<= 1) {
        int v = (tid >= off) ? sh[tid - off] : 0;
        __syncthreads();
        sh[tid] += v;
        __syncthreads();
    }
    int excl = boff[blockIdx.x] + ((tid == 0) ? 0 : sh[tid - 1]);
    if (base < NN)     { row_ptr[base]     = excl;      cursor[base]     = excl; }
    if (base + 1 < NN) { row_ptr[base + 1] = excl + d0; cursor[base + 1] = excl + d0; }
}

// ---------------- scatter edges into dst-CSR: packed (src, norm) ----------------
__global__ void k_scatter(const int* __restrict__ ei, const float* __restrict__ dinv,
                          int* __restrict__ cursor, int2* __restrict__ ed) {
    int e = blockIdx.x * blockDim.x + threadIdx.x;
    if (e >= NE) return;
    int s = ei[e], d = ei[NE + e];
    int pos = atomicAdd(&cursor[d], 1);
    int2 v; v.x = s; v.y = __float_as_int(dinv[s] * dinv[d]);
    ed[pos] = v;
}

// ---------------- layer 1 aggregate FIRST (3 channels, x is L2-resident) ----------
__global__ void k_aggx(const int* __restrict__ row_ptr, const int2* __restrict__ ed,
                       const float* __restrict__ dinv, const float* __restrict__ x,
                       float* __restrict__ aggx) {
    int n = blockIdx.x * blockDim.x + threadIdx.x;
    if (n >= NN) return;
    float di = dinv[n];
    float s2 = di * di;
    float a0 = s2 * x[n * 3], a1 = s2 * x[n * 3 + 1], a2 = s2 * x[n * 3 + 2];
    int beg = row_ptr[n], end = row_ptr[n + 1];
    for (int j = beg; j < end; ++j) {
        int2 v = ed[j];
        float w = __int_as_float(v.y);
        const float* xs = x + v.x * 3;
        a0 = fmaf(w, xs[0], a0);
        a1 = fmaf(w, xs[1], a1);
        a2 = fmaf(w, xs[2], a2);
    }
    aggx[n * 3]     = a0;
    aggx[n * 3 + 1] = a1;
    aggx[n * 3 + 2] = a2;
}

// ---------------- h1 = relu(aggx @ W1 + b1) ----------------
__global__ void k_h1(const float* __restrict__ aggx, const float* __restrict__ W1,
                     const float* __restrict__ b1, float* __restrict__ h1) {
    int t = blockIdx.x * blockDim.x + threadIdx.x;
    if (t >= NN * C_H1) return;
    int n = t >> 6, c = t & 63;
    float v = aggx[n * 3] * W1[c] + aggx[n * 3 + 1] * W1[64 + c]
            + aggx[n * 3 + 2] * W1[128 + c] + b1[c];
    h1[t] = fmaxf(v, 0.f);
}

// ---------------- layer 2 aggregate (64 channels): agg1 = Ahat @ h1 --------------
__global__ void k_gather2(const int* __restrict__ row_ptr, const int2* __restrict__ ed,
                          const float* __restrict__ dinv, const float* __restrict__ h1,
                          float* __restrict__ agg1) {
    int t = blockIdx.x * blockDim.x + threadIdx.x;   // wave = one node (64 ch)
    if (t >= NN * C_H1) return;
    int n = t >> 6, c = t & 63;
    float di = dinv[n];
    float acc = di * di * h1[t];                     // self-loop
    int beg = row_ptr[n], end = row_ptr[n + 1];
    int j = beg;
    for (; j + 3 < end; j += 4) {
        int2 v0 = ed[j], v1 = ed[j + 1], v2 = ed[j + 2], v3 = ed[j + 3];
        float f0 = h1[(v0.x << 6) + c];
        float f1 = h1[(v1.x << 6) + c];
        float f2 = h1[(v2.x << 6) + c];
        float f3 = h1[(v3.x << 6) + c];
        acc = fmaf(__int_as_float(v0.y), f0, acc);
        acc = fmaf(__int_as_float(v1.y), f1, acc);
        acc = fmaf(__int_as_float(v2.y), f2, acc);
        acc = fmaf(__int_as_float(v3.y), f3, acc);
    }
    for (; j < end; ++j) {
        int2 v = ed[j];
        acc = fmaf(__int_as_float(v.y), h1[(v.x << 6) + c], acc);
    }
    agg1[t] = acc;   // NO bias/relu here: h2 = relu(agg1 @ W2 + b2)
}

// ---------------- fused: h2 = relu(agg1 @ W2 + b2), pooled += h2 -----------------
__global__ void k_mm2pool(const float* __restrict__ agg1, const float* __restrict__ W2,
                          const float* __restrict__ b2, const int* __restrict__ batch,
                          float* __restrict__ pooled) {
    __shared__ float w[C_H1 * C_H2];                 // 32 KiB
    int tid = threadIdx.x;
    for (int i = tid; i < C_H1 * C_H2; i += 256) w[i] = W2[i];
    __syncthreads();
    int c = tid & 127, half = tid >> 7;
    int base = blockIdx.x * 16;                      // NN % 16 == 0
    float bias = b2[c];
    int run_g = -1;
    float run_sum = 0.f;
    for (int i = half; i < 16; i += 2) {
        int n = base + i;
        const float* a = agg1 + (n << 6);
        float acc = bias;
#pragma unroll
        for (int k = 0; k < C_H1; ++k)
            acc = fmaf(a[k], w[(k << 7) + c], acc);
        float h2 = fmaxf(acc, 0.f);
        int g = batch[n];
        if (g != run_g) {
            if (run_g >= 0) atomicAdd(&pooled[(run_g << 7) + c], run_sum);
            run_g = g; run_sum = h2;
        } else {
            run_sum += h2;
        }
    }
    if (run_g >= 0) atomicAdd(&pooled[(run_g << 7) + c], run_sum);
}

// ---------------- FC: out = (pooled/cnt) @ Wfc + bfc ----------------
__device__ __forceinline__ int lower_bound(const int* __restrict__ a, int n, int key) {
    int lo = 0, hi = n;
    while (lo < hi) { int mid = (lo + hi) >> 1; if (a[mid] < key) lo = mid + 1; else hi = mid; }
    return lo;
}

__global__ void k_fc(const float* __restrict__ pooled, const int* __restrict__ batch,
                     const float* __restrict__ Wfc, const float* __restrict__ bfc,
                     float* __restrict__ out) {
    int t = blockIdx.x * blockDim.x + threadIdx.x;
    if (t >= NG * C_OUT) return;
    int g = t >> 1, o = t & 1;
    int start = lower_bound(batch, NN, g);
    int end   = lower_bound(batch, NN, g + 1);
    float inv = 1.f / fmaxf((float)(end - start), 1.f);
    float s = bfc[o];
    for (int cc = 0; cc < C_H2; ++cc)
        s = fmaf(pooled[(g << 7) + cc] * inv, Wfc[cc * C_OUT + o], s);
    out[t] = s;
}

extern "C" void kernel_launch(void* const* d_in, const int* in_sizes, int n_in,
                              void* d_out, int out_size, void* d_ws, size_t ws_size,
                              hipStream_t stream) {
    const float* x     = (const float*)d_in[0];
    const int*   ei    = (const int*)d_in[1];   // [2, E]: row0 = src, row1 = dst
    const int*   batch = (const int*)d_in[2];
    const float* W1    = (const float*)d_in[3];
    const float* b1    = (const float*)d_in[4];
    const float* W2    = (const float*)d_in[5];
    const float* b2    = (const float*)d_in[6];
    const float* Wfc   = (const float*)d_in[7];
    const float* bfc   = (const float*)d_in[8];
    float* out = (float*)d_out;

    // workspace carve-out (~66 MB)
    char* p = (char*)d_ws;
    auto alloc = [&](size_t bytes) { char* r = p; p += (bytes + 255) & ~size_t(255); return r; };
    int*   deg     = (int*)  alloc((size_t)NN * 4);
    float* dinv    = (float*)alloc((size_t)NN * 4);
    int*   row_ptr = (int*)  alloc((size_t)(NN + 1) * 4);
    int*   cursor  = (int*)  alloc((size_t)NN * 4);
    int*   bsum    = (int*)  alloc((size_t)SCAN_B * 4);
    int*   boff    = (int*)  alloc((size_t)SCAN_B * 4);
    int2*  ed      = (int2*) alloc((size_t)NE * 8);
    float* aggx    = (float*)alloc((size_t)NN * 3 * 4);
    float* h1      = (float*)alloc((size_t)NN * C_H1 * 4);
    float* agg1    = (float*)alloc((size_t)NN * C_H1 * 4);
    float* pooled  = (float*)alloc((size_t)NG * C_H2 * 4);

    hipMemsetAsync(deg, 0, (size_t)NN * 4, stream);
    hipMemsetAsync(pooled, 0, (size_t)NG * C_H2 * 4, stream);
    k_deg    <<<NE / 256, 256, 0, stream>>>(ei, deg);
    k_dinv   <<<(NN + 255) / 256, 256, 0, stream>>>(deg, dinv);
    k_bsum   <<<SCAN_B, 256, 0, stream>>>(deg, bsum);
    k_bscan  <<<1, 256, 0, stream>>>(bsum, boff, row_ptr);
    k_bwrite <<<SCAN_B, 256, 0, stream>>>(deg, boff, row_ptr, cursor);
    k_scatter<<<NE / 256, 256, 0, stream>>>(ei, dinv, cursor, ed);
    k_aggx   <<<(NN + 255) / 256, 256, 0, stream>>>(row_ptr, ed, dinv, x, aggx);
    k_h1     <<<(NN * C_H1) / 256, 256, 0, stream>>>(aggx, W1, b1, h1);
    k_gather2<<<(NN * C_H1) / 256, 256, 0, stream>>>(row_ptr, ed, dinv, h1, agg1);
    k_mm2pool<<<NN / 16, 256, 0, stream>>>(agg1, W2, b2, batch, pooled);
    k_fc     <<<(NG * C_OUT + 255) / 256, 256, 0, stream>>>(pooled, batch, Wfc, bfc, out);
}